// Round 3
// baseline (1185.220 us; speedup 1.0000x reference)
//
#include <hip/hip_runtime.h>
#include <hip/hip_bf16.h>
#include <cstdint>

#define N_DIM 10000
#define P_DIM 8000
#define L_DIM 100
#define KP    128
#define LAM   0.01
#define DELTA 0.001f
#define N_PAD 10112   // 79*128
#define P_PAD 8064    // 63*128

typedef unsigned short u16;
typedef __bf16 bf16x8 __attribute__((ext_vector_type(8)));
typedef float  f32x4  __attribute__((ext_vector_type(4)));
typedef unsigned int u32x4 __attribute__((ext_vector_type(4)));

static __device__ __forceinline__ u16 f2bf(float f) {
  unsigned int u = __float_as_uint(f);
  u += 0x7FFFu + ((u >> 16) & 1u);
  return (u16)(u >> 16);
}
static __device__ __forceinline__ float sigmoidf_(float x) {
  return 1.0f / (1.0f + __expf(-x));
}

// ---- prep: et_sym (L×L), scalar constants, zero accumulators ----
__global__ void k_prep(const float* __restrict__ eta, const float* __restrict__ kappa,
                       const float* __restrict__ rho, float* __restrict__ et,
                       float* __restrict__ consts, double* __restrict__ accs) {
  int tid = threadIdx.x;
  for (int idx = tid; idx < L_DIM * L_DIM; idx += blockDim.x) {
    int i = idx / L_DIM, j = idx % L_DIM;
    et[idx] = 0.5f * (sigmoidf_(eta[idx]) + sigmoidf_(eta[j * L_DIM + i]));
  }
  if (tid == 0) {
    float k = sigmoidf_(kappa[0]);
    float r = sigmoidf_(rho[0]);
    consts[0] = (1.f - r) * (1.f - k); // c2a (also c3a)
    consts[1] = (1.f - r) * k;        // c2b
    consts[2] = r;
    accs[0] = 0.0;
    accs[1] = 0.0;
  }
}

// ---- per-gene row: softmax(theta), theta_, tmp = th @ et  (bf16, K padded to 128) ----
__global__ void k_rows(const float* __restrict__ theta, const float* __restrict__ gscal,
                       const float* __restrict__ et,
                       u16* __restrict__ th_pad, u16* __restrict__ thp_pad,
                       u16* __restrict__ tmp_pad) {
  int row = blockIdx.x;
  int t = threadIdx.x; // 0..63
  size_t ro = (size_t)row * KP;
  if (row >= P_DIM) {
    th_pad[ro + t] = 0;  th_pad[ro + t + 64] = 0;
    thp_pad[ro + t] = 0; thp_pad[ro + t + 64] = 0;
    tmp_pad[ro + t] = 0; tmp_pad[ro + t + 64] = 0;
    return;
  }
  __shared__ float th_s[L_DIM];
  const float* tr = theta + (size_t)row * L_DIM;
  bool hi_ok = (t + 64) < L_DIM;
  float v0 = tr[t];
  float v1 = hi_ok ? tr[t + 64] : -3.4e38f;
  float m = fmaxf(v0, v1);
  #pragma unroll
  for (int off = 32; off; off >>= 1) m = fmaxf(m, __shfl_xor(m, off, 64));
  float e0 = __expf(v0 - m);
  float e1 = hi_ok ? __expf(v1 - m) : 0.f;
  float s = e0 + e1;
  #pragma unroll
  for (int off = 32; off; off >>= 1) s += __shfl_xor(s, off, 64);
  float inv = 1.0f / s;
  float th0 = e0 * inv, th1 = e1 * inv;
  th_s[t] = th0;
  if (hi_ok) th_s[t + 64] = th1;
  float g = sigmoidf_(gscal[row]) + DELTA;
  th_pad[ro + t]       = f2bf(th0);
  th_pad[ro + t + 64]  = hi_ok ? f2bf(th1) : (u16)0;
  thp_pad[ro + t]      = f2bf(th0 * g);
  thp_pad[ro + t + 64] = hi_ok ? f2bf(th1 * g) : (u16)0;
  __syncthreads();
  float t0 = 0.f, t1 = 0.f;
  for (int l = 0; l < L_DIM; ++l) {
    float w = th_s[l];
    t0 += w * et[l * L_DIM + t];
    if (hi_ok) t1 += w * et[l * L_DIM + t + 64];
  }
  tmp_pad[ro + t]      = f2bf(t0);
  tmp_pad[ro + t + 64] = hi_ok ? f2bf(t1) : (u16)0;
}

// ---- a = exp(alpha), bf16, padded ----
__global__ void k_alpha(const float* __restrict__ alpha, u16* __restrict__ a_pad) {
  int idx = blockIdx.x * blockDim.x + threadIdx.x;
  if (idx >= N_PAD * KP) return;
  int row = idx >> 7, col = idx & 127;
  u16 v = 0;
  if (row < N_DIM && col < L_DIM) v = f2bf(__expf(alpha[(size_t)row * L_DIM + col]));
  a_pad[idx] = v;
}

// ---- GEMM1: recon = a @ theta_^T fused with term1 reduction ----
__global__ __launch_bounds__(256) void k_gemm1(const u16* __restrict__ A, const u16* __restrict__ B,
                                               const float* __restrict__ X, double* __restrict__ accs) {
  int tn = blockIdx.x;  // P tiles (63)
  int tm = blockIdx.y;  // N tiles (79)
  int wave = threadIdx.x >> 6, lane = threadIdx.x & 63;
  int wm = wave >> 1, wn = wave & 1;
  int row0 = tm * 128 + wm * 64;
  int col0 = tn * 128 + wn * 64;
  int lr = lane & 15, lk = lane >> 4;
  f32x4 acc[4][4] = {};
  const u16* Ab = A + (size_t)(row0 + lr) * KP + lk * 8;
  const u16* Bb = B + (size_t)(col0 + lr) * KP + lk * 8;
  #pragma unroll
  for (int kk = 0; kk < 4; ++kk) {
    bf16x8 af[4], bfr[4];
    #pragma unroll
    for (int mi = 0; mi < 4; ++mi)
      af[mi] = __builtin_bit_cast(bf16x8, *(const u32x4*)(Ab + (size_t)mi * 16 * KP + kk * 32));
    #pragma unroll
    for (int ni = 0; ni < 4; ++ni)
      bfr[ni] = __builtin_bit_cast(bf16x8, *(const u32x4*)(Bb + (size_t)ni * 16 * KP + kk * 32));
    #pragma unroll
    for (int mi = 0; mi < 4; ++mi)
      #pragma unroll
      for (int ni = 0; ni < 4; ++ni)
        acc[mi][ni] = __builtin_amdgcn_mfma_f32_16x16x32_bf16(af[mi], bfr[ni], acc[mi][ni], 0, 0, 0);
  }
  float s = 0.f;
  #pragma unroll
  for (int mi = 0; mi < 4; ++mi) {
    int rbase = row0 + mi * 16 + lk * 4;
    #pragma unroll
    for (int ni = 0; ni < 4; ++ni) {
      int c = col0 + ni * 16 + lr;
      if (c < P_DIM) {
        #pragma unroll
        for (int j = 0; j < 4; ++j) {
          int rr = rbase + j;
          if (rr < N_DIM) {
            float recon = acc[mi][ni][j];
            float x = X[(size_t)rr * P_DIM + c];
            float lg = __logf(recon);
            s += (x > 0.f ? x * lg : 0.f) - recon;
          }
        }
      }
    }
  }
  #pragma unroll
  for (int off = 32; off; off >>= 1) s += __shfl_down(s, off, 64);
  __shared__ float red[4];
  if (lane == 0) red[wave] = s;
  __syncthreads();
  if (threadIdx.x == 0) {
    double b = (double)red[0] + (double)red[1] + (double)red[2] + (double)red[3];
    atomicAdd(&accs[0], b);
  }
}

// ---- GEMM2: mat = tmp @ th^T fused with term2+term3 reduction ----
__global__ __launch_bounds__(256) void k_gemm2(const u16* __restrict__ A, const u16* __restrict__ B,
                                               const float* __restrict__ adj, const float* __restrict__ consts,
                                               double* __restrict__ accs) {
  int tn = blockIdx.x;  // 63
  int tm = blockIdx.y;  // 63
  int wave = threadIdx.x >> 6, lane = threadIdx.x & 63;
  int wm = wave >> 1, wn = wave & 1;
  int row0 = tm * 128 + wm * 64;
  int col0 = tn * 128 + wn * 64;
  int lr = lane & 15, lk = lane >> 4;
  float c2a = consts[0], c2b = consts[1], r_ = consts[2];
  f32x4 acc[4][4] = {};
  const u16* Ab = A + (size_t)(row0 + lr) * KP + lk * 8;
  const u16* Bb = B + (size_t)(col0 + lr) * KP + lk * 8;
  #pragma unroll
  for (int kk = 0; kk < 4; ++kk) {
    bf16x8 af[4], bfr[4];
    #pragma unroll
    for (int mi = 0; mi < 4; ++mi)
      af[mi] = __builtin_bit_cast(bf16x8, *(const u32x4*)(Ab + (size_t)mi * 16 * KP + kk * 32));
    #pragma unroll
    for (int ni = 0; ni < 4; ++ni)
      bfr[ni] = __builtin_bit_cast(bf16x8, *(const u32x4*)(Bb + (size_t)ni * 16 * KP + kk * 32));
    #pragma unroll
    for (int mi = 0; mi < 4; ++mi)
      #pragma unroll
      for (int ni = 0; ni < 4; ++ni)
        acc[mi][ni] = __builtin_amdgcn_mfma_f32_16x16x32_bf16(af[mi], bfr[ni], acc[mi][ni], 0, 0, 0);
  }
  float s = 0.f;
  #pragma unroll
  for (int mi = 0; mi < 4; ++mi) {
    int rbase = row0 + mi * 16 + lk * 4;
    #pragma unroll
    for (int ni = 0; ni < 4; ++ni) {
      int c = col0 + ni * 16 + lr;
      if (c < P_DIM) {
        #pragma unroll
        for (int j = 0; j < 4; ++j) {
          int rw = rbase + j;
          if (rw < P_DIM && rw != c) {
            float mat = acc[mi][ni][j];
            float a = adj[(size_t)rw * P_DIM + c];
            float f = (a != 0.f) ? fmaf(c2a, mat, c2b) : fmaf(c2a, 1.f - mat, r_);
            s += __logf(f);
          }
        }
      }
    }
  }
  #pragma unroll
  for (int off = 32; off; off >>= 1) s += __shfl_down(s, off, 64);
  __shared__ float red[4];
  if (lane == 0) red[wave] = s;
  __syncthreads();
  if (threadIdx.x == 0) {
    double b = (double)red[0] + (double)red[1] + (double)red[2] + (double)red[3];
    atomicAdd(&accs[1], b);
  }
}

__global__ void k_final(const double* __restrict__ accs, float* __restrict__ out) {
  out[0] = (float)(-LAM * accs[0] - accs[1]);
}

extern "C" void kernel_launch(void* const* d_in, const int* in_sizes, int n_in,
                              void* d_out, int out_size, void* d_ws, size_t ws_size,
                              hipStream_t stream) {
  const float* X     = (const float*)d_in[0];
  const float* adj   = (const float*)d_in[1];
  // d_in[2] = adj_1m (derived: (1-adj)*(1-I)), d_in[3] = weights (== adj): not read
  const float* theta = (const float*)d_in[4];
  const float* alpha = (const float*)d_in[5];
  const float* eta   = (const float*)d_in[6];
  const float* gscal = (const float*)d_in[7];
  const float* kappa = (const float*)d_in[8];
  const float* rho   = (const float*)d_in[9];

  char* ws = (char*)d_ws;
  size_t off = 0;
  auto alloc = [&](size_t bytes) -> void* {
    void* p = ws + off;
    off = (off + bytes + 255) & ~(size_t)255;
    return p;
  };
  double* accs  = (double*)alloc(2 * sizeof(double));
  float* consts = (float*)alloc(8 * sizeof(float));
  float* et     = (float*)alloc((size_t)L_DIM * L_DIM * sizeof(float));
  u16* th_pad   = (u16*)alloc((size_t)P_PAD * KP * sizeof(u16));
  u16* thp_pad  = (u16*)alloc((size_t)P_PAD * KP * sizeof(u16));
  u16* tmp_pad  = (u16*)alloc((size_t)P_PAD * KP * sizeof(u16));
  u16* a_pad    = (u16*)alloc((size_t)N_PAD * KP * sizeof(u16));

  hipLaunchKernelGGL(k_prep, dim3(1), dim3(256), 0, stream, eta, kappa, rho, et, consts, accs);
  hipLaunchKernelGGL(k_rows, dim3(P_PAD), dim3(64), 0, stream, theta, gscal, et, th_pad, thp_pad, tmp_pad);
  hipLaunchKernelGGL(k_alpha, dim3((N_PAD * KP) / 256), dim3(256), 0, stream, alpha, a_pad);
  hipLaunchKernelGGL(k_gemm1, dim3(63, 79), dim3(256), 0, stream, a_pad, thp_pad, X, accs);
  hipLaunchKernelGGL(k_gemm2, dim3(63, 63), dim3(256), 0, stream, tmp_pad, th_pad, adj, consts, accs);
  hipLaunchKernelGGL(k_final, dim3(1), dim3(1), 0, stream, accs, (float*)d_out);
}

// Round 4
// 858.495 us; speedup vs baseline: 1.3806x; 1.3806x over previous
//
#include <hip/hip_runtime.h>
#include <hip/hip_bf16.h>
#include <cstdint>

#define N_DIM 10000
#define P_DIM 8000
#define L_DIM 100
#define LAM   0.01
#define DELTA 0.001f
#define N_PAD 10112   // 79*128
#define P_PAD 8064    // 63*128
#define NQ    158     // N_PAD/64 row-panels
#define PQ    126     // P_PAD/64

typedef unsigned short u16;
typedef unsigned int u32;
typedef __bf16 bf16x8 __attribute__((ext_vector_type(8)));
typedef float  f32x4  __attribute__((ext_vector_type(4)));
typedef unsigned int u32x4 __attribute__((ext_vector_type(4)));

// Fragment-major operand layout: fragment block f = q*16 + kk*4 + mi
//   (q = 64-row panel, kk = K/32 step, mi = 16-row group), lane l in [0,64):
//   element offset (f*64 + l)*8 holds 8 bf16 of
//   row = q*64 + mi*16 + (l&15), cols kk*32 + (l>>4)*8 .. +7
// -> a wave's fragment load is 1KB fully contiguous.

static __device__ __forceinline__ u16 f2bf(float f) {
  u32 u = __float_as_uint(f);
  u += 0x7FFFu + ((u >> 16) & 1u);
  return (u16)(u >> 16);
}
static __device__ __forceinline__ float sigmoidf_(float x) {
  return 1.0f / (1.0f + __expf(-x));
}

// ---- prep: et_sym (L×L), scalar constants, zero accumulators ----
__global__ void k_prep(const float* __restrict__ eta, const float* __restrict__ kappa,
                       const float* __restrict__ rho, float* __restrict__ et,
                       float* __restrict__ consts, double* __restrict__ accs) {
  int tid = threadIdx.x;
  for (int idx = tid; idx < L_DIM * L_DIM; idx += blockDim.x) {
    int i = idx / L_DIM, j = idx % L_DIM;
    et[idx] = 0.5f * (sigmoidf_(eta[idx]) + sigmoidf_(eta[j * L_DIM + i]));
  }
  if (tid == 0) {
    float k = sigmoidf_(kappa[0]);
    float r = sigmoidf_(rho[0]);
    consts[0] = (1.f - r) * (1.f - k); // c2a
    consts[1] = (1.f - r) * k;        // c2b
    consts[2] = r;
    accs[0] = 0.0;
    accs[1] = 0.0;
  }
}

// ---- per-gene row: softmax(theta), theta_, tmp = th@et; write fragment-major bf16 ----
__global__ void k_rows(const float* __restrict__ theta, const float* __restrict__ gscal,
                       const float* __restrict__ et,
                       u16* __restrict__ th_f, u16* __restrict__ thp_f,
                       u16* __restrict__ tmp_f) {
  int row = blockIdx.x;   // 0 .. P_PAD-1
  int t = threadIdx.x;    // 0..63
  __shared__ float th_row[128], thp_row[128], tmp_row[128];
  th_row[t] = 0.f;  th_row[t + 64] = 0.f;
  thp_row[t] = 0.f; thp_row[t + 64] = 0.f;
  tmp_row[t] = 0.f; tmp_row[t + 64] = 0.f;
  if (row < P_DIM) {
    const float* tr = theta + (size_t)row * L_DIM;
    bool hi = (t + 64) < L_DIM;
    float v0 = tr[t];
    float v1 = hi ? tr[t + 64] : -3.4e38f;
    float m = fmaxf(v0, v1);
    #pragma unroll
    for (int off = 32; off; off >>= 1) m = fmaxf(m, __shfl_xor(m, off, 64));
    float e0 = __expf(v0 - m);
    float e1 = hi ? __expf(v1 - m) : 0.f;
    float s = e0 + e1;
    #pragma unroll
    for (int off = 32; off; off >>= 1) s += __shfl_xor(s, off, 64);
    float inv = 1.0f / s;
    float th0 = e0 * inv, th1 = e1 * inv;
    float g = sigmoidf_(gscal[row]) + DELTA;
    th_row[t] = th0; thp_row[t] = th0 * g;
    if (hi) { th_row[t + 64] = th1; thp_row[t + 64] = th1 * g; }
    __syncthreads();
    float t0 = 0.f, t1 = 0.f;
    for (int l = 0; l < L_DIM; ++l) {
      float w = th_row[l];
      t0 += w * et[l * L_DIM + t];
      if (hi) t1 += w * et[l * L_DIM + t + 64];
    }
    tmp_row[t] = t0;
    if (hi) tmp_row[t + 64] = t1;
  }
  __syncthreads();
  if (t < 48) {
    int arr = t >> 4, c8 = t & 15;
    const float* src = (arr == 0) ? th_row : (arr == 1) ? thp_row : tmp_row;
    u16* dst = (arr == 0) ? th_f : (arr == 1) ? thp_f : tmp_f;
    int q = row >> 6, mi = (row >> 4) & 3, llo = row & 15;
    int kk = c8 >> 2, lhi = c8 & 3;
    size_t off = ((size_t)((q * 16 + kk * 4 + mi) * 64 + lhi * 16 + llo)) * 8;
    u32x4 w;
    #pragma unroll
    for (int i = 0; i < 4; ++i) {
      u16 lo = f2bf(src[c8 * 8 + 2 * i]);
      u16 hi2 = f2bf(src[c8 * 8 + 2 * i + 1]);
      w[i] = (u32)lo | ((u32)hi2 << 16);
    }
    *(u32x4*)(dst + off) = w;
  }
}

// ---- a = exp(alpha) -> fragment-major bf16 ----
__global__ void k_alpha(const float* __restrict__ alpha, u16* __restrict__ a_f) {
  int tid = blockIdx.x * blockDim.x + threadIdx.x;
  if (tid >= NQ * 16 * 64) return;
  int l = tid & 63, f = tid >> 6;
  int q = f >> 4, rem = f & 15, kk = rem >> 2, mi = rem & 3;
  int row = q * 64 + mi * 16 + (l & 15);
  int col = kk * 32 + (l >> 4) * 8;
  u32x4 w;
  #pragma unroll
  for (int i = 0; i < 4; ++i) {
    u16 lo = 0, hi = 0;
    int c0 = col + 2 * i, c1 = c0 + 1;
    if (row < N_DIM) {
      if (c0 < L_DIM) lo = f2bf(__expf(alpha[(size_t)row * L_DIM + c0]));
      if (c1 < L_DIM) hi = f2bf(__expf(alpha[(size_t)row * L_DIM + c1]));
    }
    w[i] = (u32)lo | ((u32)hi << 16);
  }
  *(u32x4*)(a_f + (size_t)tid * 8) = w;
}

// ---- GEMM1: recon = a @ theta_^T fused with term1 reduction ----
__global__ __launch_bounds__(256) void k_gemm1(const u16* __restrict__ A, const u16* __restrict__ B,
                                               const float* __restrict__ X, double* __restrict__ accs) {
  __shared__ float xs[4][16][68];
  __shared__ float red[4];
  int wave = threadIdx.x >> 6, lane = threadIdx.x & 63;
  int lr = lane & 15, lk = lane >> 4;
  int qA = blockIdx.y * 2 + (wave >> 1);
  int qB = blockIdx.x * 2 + (wave & 1);
  int row0 = qA * 64, col0 = qB * 64;
  const u16* Aw = A + (size_t)qA * 8192 + (size_t)lane * 8;
  const u16* Bw = B + (size_t)qB * 8192 + (size_t)lane * 8;

  int xcc = min(col0 + lr * 4, P_DIM - 4);
  float4 xl[4];
  #pragma unroll
  for (int t = 0; t < 4; ++t) {
    int r = min(row0 + t * 4 + lk, N_DIM - 1);
    xl[t] = *(const float4*)(X + (size_t)r * P_DIM + xcc);
  }

  f32x4 acc[4][4] = {};
  #pragma unroll
  for (int kk = 0; kk < 4; ++kk) {
    bf16x8 af[4], bfr[4];
    #pragma unroll
    for (int mi = 0; mi < 4; ++mi)
      af[mi] = __builtin_bit_cast(bf16x8, *(const u32x4*)(Aw + (kk * 4 + mi) * 512));
    #pragma unroll
    for (int ni = 0; ni < 4; ++ni)
      bfr[ni] = __builtin_bit_cast(bf16x8, *(const u32x4*)(Bw + (kk * 4 + ni) * 512));
    #pragma unroll
    for (int mi = 0; mi < 4; ++mi)
      #pragma unroll
      for (int ni = 0; ni < 4; ++ni)
        acc[mi][ni] = __builtin_amdgcn_mfma_f32_16x16x32_bf16(af[mi], bfr[ni], acc[mi][ni], 0, 0, 0);
  }

  float s = 0.f;
  #pragma unroll
  for (int mi = 0; mi < 4; ++mi) {
    #pragma unroll
    for (int t = 0; t < 4; ++t)
      *(float4*)&xs[wave][t * 4 + lk][lr * 4] = xl[t];
    if (mi < 3) {
      #pragma unroll
      for (int t = 0; t < 4; ++t) {
        int r = min(row0 + (mi + 1) * 16 + t * 4 + lk, N_DIM - 1);
        xl[t] = *(const float4*)(X + (size_t)r * P_DIM + xcc);
      }
    }
    #pragma unroll
    for (int ni = 0; ni < 4; ++ni)
      #pragma unroll
      for (int j = 0; j < 4; ++j) {
        float x = xs[wave][lk * 4 + j][ni * 16 + lr];
        float recon = acc[mi][ni][j];
        int r = row0 + mi * 16 + lk * 4 + j;
        int c = col0 + ni * 16 + lr;
        bool valid = (r < N_DIM) && (c < P_DIM);
        float rc = valid ? recon : 1.0f;
        float xx = valid ? x : 0.0f;
        s += xx * __logf(rc) - (valid ? recon : 0.0f);
      }
  }
  #pragma unroll
  for (int off = 32; off; off >>= 1) s += __shfl_down(s, off, 64);
  if (lane == 0) red[wave] = s;
  __syncthreads();
  if (threadIdx.x == 0) {
    double b = (double)red[0] + (double)red[1] + (double)red[2] + (double)red[3];
    atomicAdd(&accs[0], b);
  }
}

// ---- GEMM2: mat = tmp @ th^T fused with term2+term3 reduction ----
__global__ __launch_bounds__(256) void k_gemm2(const u16* __restrict__ A, const u16* __restrict__ B,
                                               const float* __restrict__ adj, const float* __restrict__ consts,
                                               double* __restrict__ accs) {
  __shared__ float xs[4][16][68];
  __shared__ float red[4];
  int wave = threadIdx.x >> 6, lane = threadIdx.x & 63;
  int lr = lane & 15, lk = lane >> 4;
  int qA = blockIdx.y * 2 + (wave >> 1);
  int qB = blockIdx.x * 2 + (wave & 1);
  int row0 = qA * 64, col0 = qB * 64;
  const u16* Aw = A + (size_t)qA * 8192 + (size_t)lane * 8;
  const u16* Bw = B + (size_t)qB * 8192 + (size_t)lane * 8;
  float c2a = consts[0], c2b = consts[1], r_ = consts[2];
  float c3c = c2a + r_;   // c2a*(1-mat)+r = -c2a*mat + (c2a+r)

  int xcc = min(col0 + lr * 4, P_DIM - 4);
  float4 xl[4];
  #pragma unroll
  for (int t = 0; t < 4; ++t) {
    int r = min(row0 + t * 4 + lk, P_DIM - 1);
    xl[t] = *(const float4*)(adj + (size_t)r * P_DIM + xcc);
  }

  f32x4 acc[4][4] = {};
  #pragma unroll
  for (int kk = 0; kk < 4; ++kk) {
    bf16x8 af[4], bfr[4];
    #pragma unroll
    for (int mi = 0; mi < 4; ++mi)
      af[mi] = __builtin_bit_cast(bf16x8, *(const u32x4*)(Aw + (kk * 4 + mi) * 512));
    #pragma unroll
    for (int ni = 0; ni < 4; ++ni)
      bfr[ni] = __builtin_bit_cast(bf16x8, *(const u32x4*)(Bw + (kk * 4 + ni) * 512));
    #pragma unroll
    for (int mi = 0; mi < 4; ++mi)
      #pragma unroll
      for (int ni = 0; ni < 4; ++ni)
        acc[mi][ni] = __builtin_amdgcn_mfma_f32_16x16x32_bf16(af[mi], bfr[ni], acc[mi][ni], 0, 0, 0);
  }

  float s = 0.f;
  #pragma unroll
  for (int mi = 0; mi < 4; ++mi) {
    #pragma unroll
    for (int t = 0; t < 4; ++t)
      *(float4*)&xs[wave][t * 4 + lk][lr * 4] = xl[t];
    if (mi < 3) {
      #pragma unroll
      for (int t = 0; t < 4; ++t) {
        int r = min(row0 + (mi + 1) * 16 + t * 4 + lk, P_DIM - 1);
        xl[t] = *(const float4*)(adj + (size_t)r * P_DIM + xcc);
      }
    }
    #pragma unroll
    for (int ni = 0; ni < 4; ++ni)
      #pragma unroll
      for (int j = 0; j < 4; ++j) {
        float a = xs[wave][lk * 4 + j][ni * 16 + lr];
        float mat = acc[mi][ni][j];
        int r = row0 + mi * 16 + lk * 4 + j;
        int c = col0 + ni * 16 + lr;
        bool valid = (r < P_DIM) && (c < P_DIM) && (r != c);
        float f = (a != 0.f) ? fmaf(c2a, mat, c2b) : fmaf(-c2a, mat, c3c);
        f = valid ? f : 1.0f;
        s += __logf(f);
      }
  }
  #pragma unroll
  for (int off = 32; off; off >>= 1) s += __shfl_down(s, off, 64);
  if (lane == 0) red[wave] = s;
  __syncthreads();
  if (threadIdx.x == 0) {
    double b = (double)red[0] + (double)red[1] + (double)red[2] + (double)red[3];
    atomicAdd(&accs[1], b);
  }
}

__global__ void k_final(const double* __restrict__ accs, float* __restrict__ out) {
  out[0] = (float)(-LAM * accs[0] - accs[1]);
}

extern "C" void kernel_launch(void* const* d_in, const int* in_sizes, int n_in,
                              void* d_out, int out_size, void* d_ws, size_t ws_size,
                              hipStream_t stream) {
  const float* X     = (const float*)d_in[0];
  const float* adj   = (const float*)d_in[1];
  // d_in[2] = adj_1m (derived), d_in[3] = weights (== adj): not read
  const float* theta = (const float*)d_in[4];
  const float* alpha = (const float*)d_in[5];
  const float* eta   = (const float*)d_in[6];
  const float* gscal = (const float*)d_in[7];
  const float* kappa = (const float*)d_in[8];
  const float* rho   = (const float*)d_in[9];

  char* ws = (char*)d_ws;
  size_t off = 0;
  auto alloc = [&](size_t bytes) -> void* {
    void* p = ws + off;
    off = (off + bytes + 255) & ~(size_t)255;
    return p;
  };
  double* accs  = (double*)alloc(2 * sizeof(double));
  float* consts = (float*)alloc(8 * sizeof(float));
  float* et     = (float*)alloc((size_t)L_DIM * L_DIM * sizeof(float));
  u16* th_f     = (u16*)alloc((size_t)PQ * 16 * 64 * 8 * sizeof(u16));
  u16* thp_f    = (u16*)alloc((size_t)PQ * 16 * 64 * 8 * sizeof(u16));
  u16* tmp_f    = (u16*)alloc((size_t)PQ * 16 * 64 * 8 * sizeof(u16));
  u16* a_f      = (u16*)alloc((size_t)NQ * 16 * 64 * 8 * sizeof(u16));

  hipLaunchKernelGGL(k_prep, dim3(1), dim3(256), 0, stream, eta, kappa, rho, et, consts, accs);
  hipLaunchKernelGGL(k_rows, dim3(P_PAD), dim3(64), 0, stream, theta, gscal, et, th_f, thp_f, tmp_f);
  hipLaunchKernelGGL(k_alpha, dim3((NQ * 16 * 64 + 255) / 256), dim3(256), 0, stream, alpha, a_f);
  hipLaunchKernelGGL(k_gemm1, dim3(63, 79), dim3(256), 0, stream, a_f, thp_f, X, accs);
  hipLaunchKernelGGL(k_gemm2, dim3(63, 63), dim3(256), 0, stream, tmp_f, th_f, adj, consts, accs);
  hipLaunchKernelGGL(k_final, dim3(1), dim3(1), 0, stream, accs, (float*)d_out);
}